// Round 2
// baseline (1367.951 us; speedup 1.0000x reference)
//
#include <hip/hip_runtime.h>
#include <hip/hip_bf16.h>

// GQA + fused QK-RMSNorm, MI355X. All heavy math via bf16 MFMA 16x16x32.
//
// Round-2 fixes vs round 1 (NaN):
//  * attn P LDS round-trip had NO barrier between bf16 stores and short8
//    vector reads -> TBAA lets the compiler hoist the ds_read above the
//    writes -> uninitialized LDS -> NaN. Now: __syncthreads() between, and
//    ALL LDS is unsigned-short bit arrays accessed via may_alias typedefs.
//  * dtype hedge: device-side detector sniffs whether inputs are f32 or
//    bf16; load/store paths branch (wave-uniform) on the flag in d_ws.

typedef short short8 __attribute__((ext_vector_type(8)));
typedef short8 short8a __attribute__((may_alias));
typedef float f32x4 __attribute__((ext_vector_type(4)));
typedef float float4v __attribute__((ext_vector_type(4)));
typedef unsigned int uinta __attribute__((may_alias));
typedef unsigned short u16;

__device__ __forceinline__ u16 f2bf(float x) {          // RNE f32 -> bf16 bits
    unsigned u = __float_as_uint(x);
    u += 0x7fffu + ((u >> 16) & 1u);
    return (u16)(u >> 16);
}
__device__ __forceinline__ float bf2f(u16 b) {
    return __uint_as_float(((unsigned)b) << 16);
}

// --------------------------------------------------------------------------
// dtype detector: read query as f32; sane exponents -> f32 (flag=1) else bf16.
__global__ void detect_dtype(const unsigned* __restrict__ q, int* __restrict__ flag)
{
    unsigned bits = q[threadIdx.x];
    unsigned e = (bits >> 23) & 0xffu;
    bool sane = (e >= 90u && e <= 160u);
    unsigned long long m = __ballot(sane);
    if (threadIdx.x == 0) *flag = (__popcll(m) >= 48) ? 1 : 0;
}

// --------------------------------------------------------------------------
// GEMM: C[M,N] = A[M,K] * B[N,K]^T. a_mode/b_mode: 1 = dtype follows flag
// (f32 or bf16), 0 = always bf16. o_mode: 1 = follows flag, 0 = bf16.
#define BM 128
#define BN 128
#define BK 32
#define LDT 40   // LDS row stride (elems); 80 B rows -> 16B-aligned, 2-way banks

__global__ __launch_bounds__(256)
void gemm_bt(const void* __restrict__ Ap, const void* __restrict__ Bp,
             void* __restrict__ Cp, const int* __restrict__ flagp,
             int M, int N, int K, int a_mode, int b_mode, int o_mode)
{
    __shared__ __attribute__((aligned(16))) u16 As[BM * LDT];
    __shared__ __attribute__((aligned(16))) u16 Bs[BN * LDT];
    const int f     = *flagp;
    const bool af32 = a_mode && f;
    const bool bf32 = b_mode && f;
    const bool of32 = o_mode && f;
    const int tid  = threadIdx.x;
    const int wave = tid >> 6;
    const int lane = tid & 63;
    const int lrow = lane & 15;
    const int quad = lane >> 4;
    const int wm   = (wave >> 1) * 64;
    const int wn   = (wave & 1) * 64;
    const int m0   = blockIdx.y * BM;
    const int n0   = blockIdx.x * BN;

    f32x4 acc[4][4] = {};

    for (int k0 = 0; k0 < K; k0 += BK) {
        __syncthreads();
        for (int r = 0; r < 2; ++r) {
            int c   = tid + r * 256;
            int row = c >> 2;
            int col = (c & 3) * 8;
            size_t ga = (size_t)(m0 + row) * K + k0 + col;
            size_t gb = (size_t)(n0 + row) * K + k0 + col;
            short8 av, bv;
            if (af32) {
                float4v x0 = *(const float4v*)((const float*)Ap + ga);
                float4v x1 = *(const float4v*)((const float*)Ap + ga + 4);
                for (int i = 0; i < 4; ++i) { av[i] = (short)f2bf(x0[i]); av[i+4] = (short)f2bf(x1[i]); }
            } else {
                av = *(const short8a*)((const u16*)Ap + ga);
            }
            if (bf32) {
                float4v x0 = *(const float4v*)((const float*)Bp + gb);
                float4v x1 = *(const float4v*)((const float*)Bp + gb + 4);
                for (int i = 0; i < 4; ++i) { bv[i] = (short)f2bf(x0[i]); bv[i+4] = (short)f2bf(x1[i]); }
            } else {
                bv = *(const short8a*)((const u16*)Bp + gb);
            }
            *(short8a*)(&As[row * LDT + col]) = av;
            *(short8a*)(&Bs[row * LDT + col]) = bv;
        }
        __syncthreads();
        short8 afr[4], bfr[4];
        for (int i = 0; i < 4; ++i)
            afr[i] = *(const short8a*)(&As[(wm + i * 16 + lrow) * LDT + quad * 8]);
        for (int j = 0; j < 4; ++j)
            bfr[j] = *(const short8a*)(&Bs[(wn + j * 16 + lrow) * LDT + quad * 8]);
        for (int i = 0; i < 4; ++i)
            for (int j = 0; j < 4; ++j)
                acc[i][j] = __builtin_amdgcn_mfma_f32_16x16x32_bf16(afr[i], bfr[j], acc[i][j], 0, 0, 0);
    }

    for (int i = 0; i < 4; ++i)
        for (int j = 0; j < 4; ++j)
            for (int r = 0; r < 4; ++r) {
                int row = m0 + wm + i * 16 + quad * 4 + r;   // C/D: row=(lane>>4)*4+reg
                int col = n0 + wn + j * 16 + lrow;           //      col=lane&15
                size_t idx = (size_t)row * N + col;
                float v = acc[i][j][r];
                if (of32) ((float*)Cp)[idx] = v;
                else      ((u16*)Cp)[idx]   = f2bf(v);
            }
}

// --------------------------------------------------------------------------
// RMSNorm over contiguous 128-elem head rows (bf16 ws buffer). 4 chunks/block.
__global__ __launch_bounds__(256)
void rmsnorm128(u16* __restrict__ X, const void* __restrict__ w,
                const int* __restrict__ flagp, float outscale)
{
    const int f = *flagp;
    int chunk = blockIdx.x * 4 + (threadIdx.x >> 6);
    int lane  = threadIdx.x & 63;
    size_t base = (size_t)chunk * 128 + 2 * lane;
    unsigned xb = *(const uinta*)(X + base);
    float x0 = __uint_as_float(xb << 16);
    float x1 = __uint_as_float(xb & 0xffff0000u);
    float ss = x0 * x0 + x1 * x1;
    for (int off = 1; off < 64; off <<= 1) ss += __shfl_xor(ss, off);
    float inv = outscale * rsqrtf(ss * (1.0f / 128.0f) + 1e-6f);
    float w0, w1;
    if (f) {
        w0 = ((const float*)w)[2 * lane];
        w1 = ((const float*)w)[2 * lane + 1];
    } else {
        unsigned wb = *(const uinta*)((const u16*)w + 2 * lane);
        w0 = __uint_as_float(wb << 16);
        w1 = __uint_as_float(wb & 0xffff0000u);
    }
    unsigned ob = (unsigned)f2bf(x0 * inv * w0) | ((unsigned)f2bf(x1 * inv * w1) << 16);
    *(uinta*)(X + base) = ob;
}

// --------------------------------------------------------------------------
// Flash attention. Block=(qt:16 q-rows, kvh, b); wave g handles head kvh*4+g.
// Q scale folded into Q by rmsnorm. All ws tensors bf16 bits (u16).
#define ABN 64
#define KSS 136
#define VTS 72
#define PSS 72

__global__ __launch_bounds__(256)
void attn_fused(const u16* __restrict__ Q, const u16* __restrict__ Kb,
                const u16* __restrict__ Vb, u16* __restrict__ O,
                int Sq, int Skv)
{
    __shared__ __attribute__((aligned(16))) u16 Ks[ABN * KSS];    // [t][d]
    __shared__ __attribute__((aligned(16))) u16 Vt[128 * VTS];    // [d][t]
    __shared__ __attribute__((aligned(16))) u16 Ps[4 * 16 * PSS]; // per-wave P
    const int qt   = blockIdx.x;
    const int kvh  = blockIdx.y;
    const int b    = blockIdx.z;
    const int tid  = threadIdx.x;
    const int wave = tid >> 6;
    const int lane = tid & 63;
    const int lrow = lane & 15;
    const int quad = lane >> 4;
    const int h    = kvh * 4 + wave;
    const int q0   = qt * 16;

    short8 qf[4];
    {
        const u16* qp = Q + (size_t)(b * Sq + q0 + lrow) * 2048 + h * 128 + quad * 8;
        for (int ks = 0; ks < 4; ++ks)
            qf[ks] = *(const short8a*)(qp + ks * 32);
    }

    float mrow[4], lsum[4];
    f32x4 oacc[8] = {};
    for (int r = 0; r < 4; ++r) { mrow[r] = -1e30f; lsum[r] = 0.f; }

    u16* psw = &Ps[wave * 16 * PSS];

    for (int t0 = 0; t0 < Skv; t0 += ABN) {
        __syncthreads();
        for (int rr = 0; rr < 4; ++rr) {
            int idx  = tid + rr * 256;
            int trow = idx >> 4;
            int dcol = (idx & 15) * 8;
            *(short8a*)(&Ks[trow * KSS + dcol]) =
                *(const short8a*)(Kb + (size_t)(b * Skv + t0 + trow) * 512 + kvh * 128 + dcol);
        }
        for (int rr = 0; rr < 2; ++rr) {
            int idx = tid + rr * 256;
            int p   = idx & 31;
            int d0  = (idx >> 5) * 8;
            const u16* vp = Vb + (size_t)(b * Skv + t0 + 2 * p) * 512 + kvh * 128 + d0;
            short8 v0 = *(const short8a*)vp;
            short8 v1 = *(const short8a*)(vp + 512);
            for (int i = 0; i < 8; ++i) {
                unsigned pr = (unsigned)(u16)v0[i] | ((unsigned)(u16)v1[i] << 16);
                *(uinta*)(&Vt[(d0 + i) * VTS + 2 * p]) = pr;
            }
        }
        __syncthreads();

        // S tile [16 q x 64 t]
        f32x4 sacc[4] = {};
        for (int ks = 0; ks < 4; ++ks)
            for (int nt = 0; nt < 4; ++nt) {
                short8 bfr = *(const short8a*)(&Ks[(nt * 16 + lrow) * KSS + ks * 32 + quad * 8]);
                sacc[nt] = __builtin_amdgcn_mfma_f32_16x16x32_bf16(qf[ks], bfr, sacc[nt], 0, 0, 0);
            }

        // online softmax (row = quad*4+r; reduce over the 16 lanes of the quad)
        float alpha[4], rsum[4];
        for (int r = 0; r < 4; ++r) {
            float m = fmaxf(fmaxf(sacc[0][r], sacc[1][r]), fmaxf(sacc[2][r], sacc[3][r]));
            for (int off = 1; off < 16; off <<= 1) m = fmaxf(m, __shfl_xor(m, off));
            float mn = fmaxf(mrow[r], m);
            alpha[r] = __expf(mrow[r] - mn);
            mrow[r]  = mn;
            rsum[r]  = 0.f;
        }
        for (int nt = 0; nt < 4; ++nt)
            for (int r = 0; r < 4; ++r) {
                float pv = __expf(sacc[nt][r] - mrow[r]);
                rsum[r] += pv;
                psw[(quad * 4 + r) * PSS + nt * 16 + lrow] = f2bf(pv);
            }
        for (int r = 0; r < 4; ++r) {
            for (int off = 1; off < 16; off <<= 1) rsum[r] += __shfl_xor(rsum[r], off);
            lsum[r] = lsum[r] * alpha[r] + rsum[r];
        }
        for (int d = 0; d < 8; ++d)
            for (int r = 0; r < 4; ++r) oacc[d][r] *= alpha[r];

        // CRITICAL: order P stores before the short8 reads (round-1 NaN bug)
        __syncthreads();

        for (int ks = 0; ks < 2; ++ks) {
            short8 afr = *(const short8a*)(&psw[lrow * PSS + ks * 32 + quad * 8]);
            for (int d = 0; d < 8; ++d) {
                short8 bfr = *(const short8a*)(&Vt[(d * 16 + lrow) * VTS + ks * 32 + quad * 8]);
                oacc[d] = __builtin_amdgcn_mfma_f32_16x16x32_bf16(afr, bfr, oacc[d], 0, 0, 0);
            }
        }
    }

    for (int r = 0; r < 4; ++r) {
        float inv = 1.0f / lsum[r];
        size_t row = (size_t)(b * Sq + q0 + quad * 4 + r) * 2048 + h * 128;
        for (int d = 0; d < 8; ++d)
            O[row + d * 16 + lrow] = f2bf(oacc[d][r] * inv);
    }
}

// --------------------------------------------------------------------------
extern "C" void kernel_launch(void* const* d_in, const int* in_sizes, int n_in,
                              void* d_out, int out_size, void* d_ws, size_t ws_size,
                              hipStream_t stream)
{
    const int M  = in_sizes[0] / 2048;   // B*S = 8192
    const int Sq = 2048;
    const int Bb = M / Sq;

    char* ws = (char*)d_ws;
    int* flag = (int*)ws;
    u16* Qb = (u16*)(ws + 256);
    u16* Kb = (u16*)(ws + 256 + (size_t)M * 2048 * 2);
    u16* Vb = (u16*)(ws + 256 + (size_t)M * 2048 * 2 + (size_t)M * 512 * 2);
    u16* Ob = (u16*)(ws + 256 + (size_t)M * 2048 * 2 + (size_t)M * 512 * 4);

    dim3 blk(256);
    detect_dtype<<<1, 64, 0, stream>>>((const unsigned*)d_in[0], flag);
    // projections (inputs: dtype per flag; outputs: bf16 ws)
    gemm_bt<<<dim3(2048 / BN, M / BM), blk, 0, stream>>>(d_in[0], d_in[3], Qb, flag, M, 2048, 2048, 1, 1, 0);
    gemm_bt<<<dim3(512 / BN,  M / BM), blk, 0, stream>>>(d_in[1], d_in[4], Kb, flag, M, 512, 2048, 1, 1, 0);
    gemm_bt<<<dim3(512 / BN,  M / BM), blk, 0, stream>>>(d_in[2], d_in[5], Vb, flag, M, 512, 2048, 1, 1, 0);
    // fused QK rmsnorm (attention scale folded into Q)
    rmsnorm128<<<dim3(M * 16 / 4), blk, 0, stream>>>(Qb, d_in[7], flag, 0.08838834764831845f);
    rmsnorm128<<<dim3(M * 4 / 4),  blk, 0, stream>>>(Kb, d_in[8], flag, 1.0f);
    // attention
    attn_fused<<<dim3(Sq / 16, 4, Bb), blk, 0, stream>>>(Qb, Kb, Vb, Ob, Sq, Sq);
    // output projection (A: bf16 ws; B: flag; out: flag)
    gemm_bt<<<dim3(2048 / BN, M / BM), blk, 0, stream>>>(Ob, d_in[6], d_out, flag, M, 2048, 2048, 0, 1, 1);
}

// Round 3
// 991.478 us; speedup vs baseline: 1.3797x; 1.3797x over previous
//
#include <hip/hip_runtime.h>
#include <hip/hip_bf16.h>

// GQA + fused QK-RMSNorm, MI355X gfx950. Round 3.
//  * gemm: m97-style global_load_lds(16B) staging, XOR-swizzled unpadded LDS.
//  * attn: S^T trick -> P stays in registers (C-layout == B-frag layout of
//    16x16x16 MFMA); fixed-max softmax (scores provably <= ~11.4 since
//    ||q_hat||=1, ||k_hat||=sqrt(128)); exp2 with log2e folded into Q scale;
//    K tile staged via global_load_lds + swizzle; V transposed in regs.

typedef short short8 __attribute__((ext_vector_type(8)));
typedef short8 short8a __attribute__((may_alias));
typedef short short4v __attribute__((ext_vector_type(4)));
typedef short4v short4a __attribute__((may_alias));
typedef float f32x4 __attribute__((ext_vector_type(4)));
typedef float float4v __attribute__((ext_vector_type(4)));
typedef unsigned int uinta __attribute__((may_alias));
typedef unsigned short u16;

__device__ __forceinline__ u16 f2bf(float x) {          // RNE f32 -> bf16 bits
    unsigned u = __float_as_uint(x);
    u += 0x7fffu + ((u >> 16) & 1u);
    return (u16)(u >> 16);
}
__device__ __forceinline__ float bf2f(u16 b) {
    return __uint_as_float(((unsigned)b) << 16);
}
__device__ __forceinline__ void lds_load16(void* lds, const void* g) {
    // async global->LDS DMA: dest = wave-uniform base + lane*16
    __builtin_amdgcn_global_load_lds(
        (__attribute__((address_space(1))) unsigned int*)g,
        (__attribute__((address_space(3))) unsigned int*)lds, 16, 0, 0);
}

// --------------------------------------------------------------------------
__global__ void detect_dtype(const unsigned* __restrict__ q, int* __restrict__ flag)
{
    unsigned bits = q[threadIdx.x];
    unsigned e = (bits >> 23) & 0xffu;
    bool sane = (e >= 90u && e <= 160u);
    unsigned long long m = __ballot(sane);
    if (threadIdx.x == 0) *flag = (__popcll(m) >= 48) ? 1 : 0;
}

// --------------------------------------------------------------------------
// GEMM: C[M,N] = A[M,K]*B[N,K]^T. BM=RT*32 x BN=128 x BK=32 tile, 4 waves.
// LDS unpadded (row=32 elems=64B); 16B chunk c of row r stored at slot
// c ^ ((r>>1)&3)  -> frag ds_read_b128 is 2-way (free) instead of 8-way.
#define BN 128
#define BK 32

template<int RT>
__global__ __launch_bounds__(256)
void gemm_bt(const void* __restrict__ Ap, const void* __restrict__ Bp,
             void* __restrict__ Cp, const int* __restrict__ flagp,
             int M, int N, int K, int a_mode, int b_mode, int o_mode)
{
    constexpr int BM = RT * 32;
    __shared__ __attribute__((aligned(16))) u16 As[BM * BK];
    __shared__ __attribute__((aligned(16))) u16 Bs[BN * BK];
    const int f     = *flagp;
    const bool af32 = a_mode && f;
    const bool bf32 = b_mode && f;
    const bool of32 = o_mode && f;
    const int tid  = threadIdx.x;
    const int wave = tid >> 6;
    const int lane = tid & 63;
    const int lrow = lane & 15;
    const int quad = lane >> 4;
    const int wm   = (wave >> 1) * (RT * 16);
    const int wn   = (wave & 1) * 64;
    const int m0   = blockIdx.y * BM;
    const int n0   = blockIdx.x * BN;
    const int sel  = (lrow >> 1) & 3;      // frag-read swizzle select

    f32x4 acc[RT][4] = {};

    for (int k0 = 0; k0 < K; k0 += BK) {
        __syncthreads();
        if (!af32) {
            for (int p = 0; p < RT / 2; ++p) {       // 16 rows per wave-pass
                int seg = wave * (RT / 2) + p;
                int row = seg * 16 + (lane >> 2);
                int gch = (lane & 3) ^ ((row >> 1) & 3);
                lds_load16(&As[seg * 16 * BK],
                           (const u16*)Ap + (size_t)(m0 + row) * K + k0 + gch * 8);
            }
        } else {
            for (int it = 0; it < RT / 2; ++it) {
                int idx = tid + it * 256;
                int row = idx >> 2;
                int c   = idx & 3;
                int gch = c ^ ((row >> 1) & 3);
                const float* gp = (const float*)Ap + (size_t)(m0 + row) * K + k0 + gch * 8;
                float4v x0 = *(const float4v*)gp;
                float4v x1 = *(const float4v*)(gp + 4);
                short8 v;
                for (int i = 0; i < 4; ++i) { v[i] = (short)f2bf(x0[i]); v[i + 4] = (short)f2bf(x1[i]); }
                *(short8a*)(&As[row * BK + c * 8]) = v;
            }
        }
        if (!bf32) {
            for (int p = 0; p < 2; ++p) {
                int seg = wave * 2 + p;
                int row = seg * 16 + (lane >> 2);
                int gch = (lane & 3) ^ ((row >> 1) & 3);
                lds_load16(&Bs[seg * 16 * BK],
                           (const u16*)Bp + (size_t)(n0 + row) * K + k0 + gch * 8);
            }
        } else {
            for (int it = 0; it < 2; ++it) {
                int idx = tid + it * 256;
                int row = idx >> 2;
                int c   = idx & 3;
                int gch = c ^ ((row >> 1) & 3);
                const float* gp = (const float*)Bp + (size_t)(n0 + row) * K + k0 + gch * 8;
                float4v x0 = *(const float4v*)gp;
                float4v x1 = *(const float4v*)(gp + 4);
                short8 v;
                for (int i = 0; i < 4; ++i) { v[i] = (short)f2bf(x0[i]); v[i + 4] = (short)f2bf(x1[i]); }
                *(short8a*)(&Bs[row * BK + c * 8]) = v;
            }
        }
        __builtin_amdgcn_s_waitcnt(0);   // drain global_load_lds before barrier
        __syncthreads();

        short8 afr[RT], bfr[4];
        for (int i = 0; i < RT; ++i)
            afr[i] = *(const short8a*)(&As[(wm + i * 16 + lrow) * BK + (quad ^ sel) * 8]);
        for (int j = 0; j < 4; ++j)
            bfr[j] = *(const short8a*)(&Bs[(wn + j * 16 + lrow) * BK + (quad ^ sel) * 8]);
        for (int i = 0; i < RT; ++i)
            for (int j = 0; j < 4; ++j)
                acc[i][j] = __builtin_amdgcn_mfma_f32_16x16x32_bf16(afr[i], bfr[j], acc[i][j], 0, 0, 0);
    }

    for (int i = 0; i < RT; ++i)
        for (int j = 0; j < 4; ++j)
            for (int r = 0; r < 4; ++r) {
                int row = m0 + wm + i * 16 + quad * 4 + r;   // C/D: row=quad*4+reg
                int col = n0 + wn + j * 16 + lrow;           //      col=lane&15
                size_t idx = (size_t)row * N + col;
                float v = acc[i][j][r];
                if (of32) ((float*)Cp)[idx] = v;
                else      ((u16*)Cp)[idx]   = f2bf(v);
            }
}

// --------------------------------------------------------------------------
// RMSNorm over contiguous 128-elem head rows; 16 lanes/chunk, 16B/lane.
__global__ __launch_bounds__(256)
void rmsnorm128v(u16* __restrict__ X, const void* __restrict__ w,
                 const int* __restrict__ flagp, float outscale)
{
    const int f = *flagp;
    int t     = blockIdx.x * 256 + threadIdx.x;
    int chunk = t >> 4;
    int l16   = t & 15;
    u16* xp = X + (size_t)chunk * 128 + l16 * 8;
    short8 xv = *(const short8a*)xp;
    float xs[8]; float ss = 0.f;
    for (int i = 0; i < 8; ++i) { xs[i] = bf2f((u16)xv[i]); ss += xs[i] * xs[i]; }
    ss += __shfl_xor(ss, 1); ss += __shfl_xor(ss, 2);
    ss += __shfl_xor(ss, 4); ss += __shfl_xor(ss, 8);
    float inv = outscale * rsqrtf(ss * (1.0f / 128.0f) + 1e-6f);
    float ws[8];
    if (f) {
        float4v w0 = ((const float4v*)w)[l16 * 2];
        float4v w1 = ((const float4v*)w)[l16 * 2 + 1];
        for (int i = 0; i < 4; ++i) { ws[i] = w0[i]; ws[i + 4] = w1[i]; }
    } else {
        short8 wv = ((const short8a*)w)[l16];
        for (int i = 0; i < 8; ++i) ws[i] = bf2f((u16)wv[i]);
    }
    short8 o;
    for (int i = 0; i < 8; ++i) o[i] = (short)f2bf(xs[i] * inv * ws[i]);
    *(short8a*)xp = o;
}

// --------------------------------------------------------------------------
// Flash attention, S^T formulation. Block=(qt:16 q-rows, kvh, b); wave g ->
// head kvh*4+g. Q scale (1/sqrt(128) * log2e) folded in by rmsnorm; softmax
// uses fixed max 0 (scores bounded by ~16.4 in log2 domain; exp2 <= 9e4).
//  QK:  sacc[nt] = MFMA_16x16x32(A=K-frag, B=Q-frag) -> S^T: lane holds
//       S[q=lane&15][t=nt*16+quad*4+r]  == B-frag layout of 16x16x16 MFMA.
//  PV:  oacc[dblk] = MFMA_16x16x16(A=Vt-frag, B=P-regs) -> O^T C-layout:
//       lane holds O[q=lane&15][d=dblk*16+quad*4+r].
#define VTS 72

__global__ __launch_bounds__(256, 4)
void attn_fused(const u16* __restrict__ Q, const u16* __restrict__ Kb,
                const u16* __restrict__ Vb, u16* __restrict__ O,
                int Sq, int Skv)
{
    __shared__ __attribute__((aligned(16))) u16 Ks[64 * 128];   // [t][d] swizzled
    __shared__ __attribute__((aligned(16))) u16 Vt[128 * VTS];  // [d][t]
    const int qt   = blockIdx.x;
    const int kvh  = blockIdx.y;
    const int b    = blockIdx.z;
    const int tid  = threadIdx.x;
    const int wave = tid >> 6;
    const int lane = tid & 63;
    const int lrow = lane & 15;
    const int quad = lane >> 4;
    const int h    = kvh * 4 + wave;
    const int q0   = qt * 16;
    const int swz  = lrow & 7;

    short8 qf[4];   // B-frag: Q[q=lane&15][d=ks*32+quad*8+i]
    {
        const u16* qp = Q + (size_t)(b * Sq + q0 + lrow) * 2048 + h * 128 + quad * 8;
        for (int ks = 0; ks < 4; ++ks) qf[ks] = *(const short8a*)(qp + ks * 32);
    }

    float lsum = 0.f;
    f32x4 oacc[8] = {};

    for (int t0 = 0; t0 < Skv; t0 += 64) {
        __syncthreads();
        // K tile [64t x 128d] via global_load_lds; chunk c of row r at slot c^(r&7)
        for (int p = 0; p < 4; ++p) {
            int seg = p * 4 + wave;                 // rows seg*4 .. seg*4+3
            int row = seg * 4 + (lane >> 4);
            int gch = (lane & 15) ^ (row & 7);
            lds_load16(&Ks[seg * 4 * 128],
                       Kb + (size_t)(b * Skv + t0 + row) * 512 + kvh * 128 + gch * 8);
        }
        // V transposed: Vt[d][t] (u32 = t-pair); conflict-free writes
        for (int rr = 0; rr < 2; ++rr) {
            int idx = tid + rr * 256;
            int p   = idx & 31;
            int d0  = (idx >> 5) * 8;
            const u16* vp = Vb + (size_t)(b * Skv + t0 + 2 * p) * 512 + kvh * 128 + d0;
            short8 v0 = *(const short8a*)vp;
            short8 v1 = *(const short8a*)(vp + 512);
            for (int i = 0; i < 8; ++i) {
                unsigned pr = (unsigned)(u16)v0[i] | ((unsigned)(u16)v1[i] << 16);
                *(uinta*)(&Vt[(d0 + i) * VTS + 2 * p]) = pr;
            }
        }
        __builtin_amdgcn_s_waitcnt(0);
        __syncthreads();

        for (int nt = 0; nt < 4; ++nt) {
            // S^T 16t x 16q sub-tile
            f32x4 sacc = {};
            for (int ks = 0; ks < 4; ++ks) {
                short8 kf = *(const short8a*)(
                    &Ks[(nt * 16 + lrow) * 128 + ((ks * 4 + quad) ^ swz) * 8]);
                sacc = __builtin_amdgcn_mfma_f32_16x16x32_bf16(kf, qf[ks], sacc, 0, 0, 0);
            }
            // P = exp2(S^T) straight into B-frag registers (fixed max)
            float p0 = exp2f(sacc[0]), p1 = exp2f(sacc[1]);
            float p2 = exp2f(sacc[2]), p3 = exp2f(sacc[3]);
            lsum += (p0 + p1) + (p2 + p3);
            short4v pf;
            pf[0] = (short)f2bf(p0); pf[1] = (short)f2bf(p1);
            pf[2] = (short)f2bf(p2); pf[3] = (short)f2bf(p3);
            // O^T += V^T * P : A-frag = Vt[d=dblk*16+lane&15][t=nt*16+quad*4+i]
            for (int dblk = 0; dblk < 8; ++dblk) {
                short4v av = *(const short4a*)(
                    &Vt[(dblk * 16 + lrow) * VTS + nt * 16 + quad * 4]);
                oacc[dblk] = __builtin_amdgcn_mfma_f32_16x16x16bf16_1k(av, pf, oacc[dblk], 0, 0, 0);
            }
        }
    }

    // lsum currently per (q=lane&15, t-subset of this quad): reduce over quads
    lsum += __shfl_xor(lsum, 16);
    lsum += __shfl_xor(lsum, 32);
    float inv = 1.0f / lsum;

    // O[q=lane&15][d=dblk*16+quad*4+r]: 4 consecutive d -> 8B stores
    {
        u16* op = O + (size_t)(b * Sq + q0 + lrow) * 2048 + h * 128 + quad * 4;
        for (int dblk = 0; dblk < 8; ++dblk) {
            unsigned w0 = (unsigned)f2bf(oacc[dblk][0] * inv) |
                          ((unsigned)f2bf(oacc[dblk][1] * inv) << 16);
            unsigned w1 = (unsigned)f2bf(oacc[dblk][2] * inv) |
                          ((unsigned)f2bf(oacc[dblk][3] * inv) << 16);
            uint2 wv; wv.x = w0; wv.y = w1;
            *(uint2*)(op + dblk * 16) = wv;
        }
    }
}

// --------------------------------------------------------------------------
extern "C" void kernel_launch(void* const* d_in, const int* in_sizes, int n_in,
                              void* d_out, int out_size, void* d_ws, size_t ws_size,
                              hipStream_t stream)
{
    const int M  = in_sizes[0] / 2048;   // B*S = 8192
    const int Sq = 2048;
    const int Bb = M / Sq;

    char* ws = (char*)d_ws;
    int* flag = (int*)ws;
    u16* Qb = (u16*)(ws + 256);
    u16* Kb = (u16*)(ws + 256 + (size_t)M * 2048 * 2);
    u16* Vb = (u16*)(ws + 256 + (size_t)M * 2048 * 2 + (size_t)M * 512 * 2);
    u16* Ob = (u16*)(ws + 256 + (size_t)M * 2048 * 2 + (size_t)M * 512 * 4);

    dim3 blk(256);
    detect_dtype<<<1, 64, 0, stream>>>((const unsigned*)d_in[0], flag);
    // projections (output bf16 ws)
    gemm_bt<4><<<dim3(2048 / BN, M / 128), blk, 0, stream>>>(d_in[0], d_in[3], Qb, flag, M, 2048, 2048, 1, 1, 0);
    gemm_bt<2><<<dim3(512 / BN,  M / 64),  blk, 0, stream>>>(d_in[1], d_in[4], Kb, flag, M, 512, 2048, 1, 1, 0);
    gemm_bt<2><<<dim3(512 / BN,  M / 64),  blk, 0, stream>>>(d_in[2], d_in[5], Vb, flag, M, 512, 2048, 1, 1, 0);
    // fused QK rmsnorm; Q gets 1/sqrt(128)*log2(e) so attn uses exp2 directly
    rmsnorm128v<<<dim3(M),     blk, 0, stream>>>(Qb, d_in[7], flag, 0.12752227653159732f);
    rmsnorm128v<<<dim3(M / 4), blk, 0, stream>>>(Kb, d_in[8], flag, 1.0f);
    // attention
    attn_fused<<<dim3(Sq / 16, 4, Bb), blk, 0, stream>>>(Qb, Kb, Vb, Ob, Sq, Sq);
    // output projection
    gemm_bt<4><<<dim3(2048 / BN, M / 128), blk, 0, stream>>>(Ob, d_in[6], d_out, flag, M, 2048, 2048, 0, 1, 1);
}